// Round 5
// baseline (93.778 us; speedup 1.0000x reference)
//
#include <hip/hip_runtime.h>
#include <math.h>

#define Cc 512
#define Pp 1024
#define NROW 25088      // B*N = 8*3136
#define BM 128          // rows per block
#define BNP 256         // centroid cols per block (4 pblocks)
#define BK 64           // K tile (8 K-steps)
#define NMB 196         // real mblocks = 25088/128
#define NMB_PAD 200     // padded so mblocks group 8-per-XCD
#define BIAS 4096.f     // makes v = cn+BIAS-2dot strictly positive for packing

typedef short  bf16x8 __attribute__((ext_vector_type(8)));   // 8 bf16 = 4 VGPR
typedef float  f32x4  __attribute__((ext_vector_type(4)));
typedef unsigned short u16x8 __attribute__((ext_vector_type(8)));

__device__ __forceinline__ unsigned short bf16_rne(float f) {
    unsigned int u = __float_as_uint(f);
    return (unsigned short)((u + 0x7fffu + ((u >> 16) & 1u)) >> 16);
}

// ---------------------------------------------------------------------------
// Fused fp32 -> bf16 (RNE) conversion + row squared-norm. One wave per row.
// ---------------------------------------------------------------------------
__global__ __launch_bounds__(256) void conv_norm_kernel(
        const float* __restrict__ src, unsigned short* __restrict__ dst,
        float* __restrict__ nrm) {
    int wid  = blockIdx.x * 4 + (threadIdx.x >> 6);
    int lane = threadIdx.x & 63;
    const float4* r = (const float4*)(src + (size_t)wid * Cc);
    float4 a = r[lane * 2];
    float4 b = r[lane * 2 + 1];
    u16x8 o;
    o[0] = bf16_rne(a.x); o[1] = bf16_rne(a.y); o[2] = bf16_rne(a.z); o[3] = bf16_rne(a.w);
    o[4] = bf16_rne(b.x); o[5] = bf16_rne(b.y); o[6] = bf16_rne(b.z); o[7] = bf16_rne(b.w);
    *(u16x8*)(dst + (size_t)wid * Cc + lane * 8) = o;
    float s = a.x*a.x + a.y*a.y + a.z*a.z + a.w*a.w
            + b.x*b.x + b.y*b.y + b.z*b.z + b.w*b.w;
    #pragma unroll
    for (int m = 1; m < 64; m <<= 1) s += __shfl_xor(s, m);
    if (lane == 0) nrm[wid] = s;
}

// branch-free sorted insert of v into (t0 <= t1 <= t2), keeping smallest 3
#define TOP3_INSERT(t0, t1, t2, v)                                  \
    do {                                                            \
        float _n0 = fminf((t0), (v));                               \
        float _h0 = fmaxf((t0), (v));                               \
        float _n1 = fminf((t1), _h0);                               \
        float _h1 = fmaxf((t1), _h0);                               \
        float _n2 = fminf((t2), _h1);                               \
        (t0) = _n0; (t1) = _n1; (t2) = _n2;                         \
    } while (0)

#define GLOAD_LDS16(gp, lp)                                             \
    __builtin_amdgcn_global_load_lds(                                   \
        (const __attribute__((address_space(1))) void*)(const void*)(gp),\
        (__attribute__((address_space(3))) void*)(void*)(lp), 16, 0, 0)

// ---------------------------------------------------------------------------
// Main: 128x256 bf16 MFMA tile, BK=64, XOR-swizzled LDS, XCD-grouped P-split,
// packed-u32 3-pass top-3 epilogue (tie-safe via col-index tiebreak).
// Grid: 800 blocks (200 padded mblocks x 4 pblocks), 512 thr = 8 waves (2x4).
// Wave tile 64x64 = 4x4 fragments, 2 k-substeps -> 32 MFMA per K-step.
// ---------------------------------------------------------------------------
__global__ __launch_bounds__(512) void mfma_topk_kernel(
        const unsigned short* __restrict__ Eb, const unsigned short* __restrict__ Cb,
        const float* __restrict__ cnorm, float* __restrict__ wsTop) {
    // XCD-grouped decode: the 4 pblocks of an mblock land on one XCD
    const int xcd = blockIdx.x & 7;
    const int t   = blockIdx.x >> 3;          // 0..99
    const int mblock = ((t >> 2) << 3) | xcd; // 0..199
    const int pblock = t & 3;
    if (mblock >= NMB) return;                // uniform early-exit

    __shared__ unsigned short As[BM * BK];    // 16 KB
    __shared__ unsigned short Bs[BNP * BK];   // 32 KB
    float* tops = (float*)As;                 // aliased after main loop: [4][128][3]

    const int tid  = threadIdx.x;
    const int lane = tid & 63;
    const int w    = tid >> 6;
    const int wm   = w >> 2;       // 0..1 row half
    const int wn   = w & 3;        // 0..3 col quarter
    const int g    = lane >> 4;    // 0..3
    const int q    = lane & 15;    // 0..15
    const int qa   = q & 7;
    const int row0 = mblock * BM;
    const int p0   = pblock * BNP;

    f32x4 acc[4][4];
    #pragma unroll
    for (int m = 0; m < 4; ++m)
        #pragma unroll
        for (int n = 0; n < 4; ++n) acc[m][n] = (f32x4){0.f, 0.f, 0.f, 0.f};

    // K loop: 8 steps of BK=64. A: 1024 16B-chunks, B: 2048. Source
    // pre-swizzled (slot ^= row&7), LDS dest linear, reader applies same XOR.
    for (int kk = 0; kk < Cc; kk += BK) {
        __syncthreads();    // previous step's LDS reads done
        #pragma unroll
        for (int it = 0; it < 2; ++it) {
            int c = tid + it * 512;
            int row = c >> 3;
            int sg  = (c & 7) ^ (row & 7);
            GLOAD_LDS16(Eb + (size_t)(row0 + row) * Cc + kk + sg * 8,
                        (char*)As + c * 16);
        }
        #pragma unroll
        for (int it = 0; it < 4; ++it) {
            int c = tid + it * 512;
            int row = c >> 3;
            int sg  = (c & 7) ^ (row & 7);
            GLOAD_LDS16(Cb + (size_t)(p0 + row) * Cc + kk + sg * 8,
                        (char*)Bs + c * 16);
        }
        __syncthreads();    // staging complete

        #pragma unroll
        for (int ks = 0; ks < 2; ++ks) {
            const int slot = ((ks << 2) | g) ^ qa;   // swizzled 16B slot
            bf16x8 a[4], b[4];
            #pragma unroll
            for (int m = 0; m < 4; ++m)
                a[m] = *(const bf16x8*)((const char*)As +
                        (wm * 64 + m * 16 + q) * 128 + slot * 16);
            #pragma unroll
            for (int n = 0; n < 4; ++n)
                b[n] = *(const bf16x8*)((const char*)Bs +
                        (wn * 64 + n * 16 + q) * 128 + slot * 16);
            #pragma unroll
            for (int m = 0; m < 4; ++m)
                #pragma unroll
                for (int n = 0; n < 4; ++n)
                    acc[m][n] = __builtin_amdgcn_mfma_f32_16x16x32_bf16(
                        a[m], b[n], acc[m][n], 0, 0, 0);
        }
    }

    // ---- epilogue: packed-u32 3-pass top-3 of v = cn + BIAS - 2*dot ----
    float cnb[4];
    unsigned int col[4];
    #pragma unroll
    for (int n = 0; n < 4; ++n) {
        cnb[n] = cnorm[p0 + wn * 64 + n * 16 + q] + BIAS;
        col[n] = (unsigned int)(wn * 64 + n * 16 + q);    // 0..255, 8 bits
    }

    __syncthreads();   // all waves done reading As before tops-alias writes

    #pragma unroll
    for (int m = 0; m < 4; ++m) {
        #pragma unroll
        for (int r = 0; r < 4; ++r) {
            unsigned int u[4];
            #pragma unroll
            for (int n = 0; n < 4; ++n) {
                float v = fmaf(-2.f, acc[m][n][r], cnb[n]);   // > 0 guaranteed
                u[n] = (__float_as_uint(v) & 0xFFFFFF00u) | col[n];
            }
            // pass 1: global min (packed order == float order for positives)
            unsigned int w0 = min(min(u[0], u[1]), min(u[2], u[3]));
            #pragma unroll
            for (int mask = 1; mask <= 8; mask <<= 1)
                w0 = min(w0, (unsigned int)__shfl_xor((int)w0, mask));
            // pass 2: mask exact winner (unique col tiebreak), min again
            unsigned int v1[4];
            #pragma unroll
            for (int n = 0; n < 4; ++n) v1[n] = (u[n] == w0) ? 0xFFFFFFFFu : u[n];
            unsigned int w1 = min(min(v1[0], v1[1]), min(v1[2], v1[3]));
            #pragma unroll
            for (int mask = 1; mask <= 8; mask <<= 1)
                w1 = min(w1, (unsigned int)__shfl_xor((int)w1, mask));
            // pass 3
            unsigned int v2[4];
            #pragma unroll
            for (int n = 0; n < 4; ++n) v2[n] = (v1[n] == w1) ? 0xFFFFFFFFu : v1[n];
            unsigned int w2 = min(min(v2[0], v2[1]), min(v2[2], v2[3]));
            #pragma unroll
            for (int mask = 1; mask <= 8; mask <<= 1)
                w2 = min(w2, (unsigned int)__shfl_xor((int)w2, mask));

            if (q == 0) {
                int rl = wm * 64 + m * 16 + g * 4 + r;
                float* dst = tops + (wn * BM + rl) * 3;
                dst[0] = __uint_as_float(w0 & 0xFFFFFF00u) - BIAS;
                dst[1] = __uint_as_float(w1 & 0xFFFFFF00u) - BIAS;
                dst[2] = __uint_as_float(w2 & 0xFFFFFF00u) - BIAS;
            }
        }
    }
    __syncthreads();

    if (tid < BM) {
        const float* p = tops + tid * 3;
        float a0 = p[0], a1 = p[1], a2 = p[2];
        #pragma unroll
        for (int x = 1; x < 4; ++x) {
            const float* px = tops + (x * BM + tid) * 3;
            TOP3_INSERT(a0, a1, a2, px[0]);
            TOP3_INSERT(a0, a1, a2, px[1]);
            TOP3_INSERT(a0, a1, a2, px[2]);
        }
        float* dst = wsTop + (size_t)(row0 + tid) * 12 + pblock * 3;
        dst[0] = a0; dst[1] = a1; dst[2] = a2;
    }
}

// ---------------------------------------------------------------------------
// Final merge: fold 4 pblocks' top3, add row norm, sqrt + softmin, store.
// ---------------------------------------------------------------------------
__global__ __launch_bounds__(256) void merge_kernel(
        const float* __restrict__ wsTop, const float* __restrict__ fnorm,
        float* __restrict__ out) {
    int r = blockIdx.x * 256 + threadIdx.x;      // 25088 = 98*256 exact
    const float* p = wsTop + (size_t)r * 12;
    float t0 = p[0], t1 = p[1], t2 = p[2];
    #pragma unroll
    for (int pb = 1; pb < 4; ++pb) {
        TOP3_INSERT(t0, t1, t2, p[pb * 3 + 0]);
        TOP3_INSERT(t0, t1, t2, p[pb * 3 + 1]);
        TOP3_INSERT(t0, t1, t2, p[pb * 3 + 2]);
    }
    float fn = fnorm[r];
    float d0 = sqrtf(fmaxf(fn + t0, 0.f));
    float d1 = sqrtf(fmaxf(fn + t1, 0.f));
    float d2 = sqrtf(fmaxf(fn + t2, 0.f));
    float w0 = 1.f / (1.f + __expf(d0 - d1) + __expf(d0 - d2));
    out[r] = w0 * d0;
}

extern "C" void kernel_launch(void* const* d_in, const int* in_sizes, int n_in,
                              void* d_out, int out_size, void* d_ws, size_t ws_size,
                              hipStream_t stream) {
    (void)in_sizes; (void)n_in; (void)out_size; (void)ws_size;
    const float* embeds    = (const float*)d_in[0];   // [8,3136,512] fp32
    const float* centroids = (const float*)d_in[1];   // [1024,512]  fp32
    float* out = (float*)d_out;

    // ws layout (bytes):
    //   cnorm  @ 0         (4 KB)
    //   fnorm  @ 4096      (100,352 B)
    //   wsTop  @ 104448    (25088*4*3*4 = 1,204,224 B)  [row][pblock][3]
    //   Eb     @ 2512896   (25,690,112 B bf16)
    //   Cb     @ 28203008  (1,048,576 B bf16)           total ~27.9 MB
    char* ws = (char*)d_ws;
    float*          cnorm = (float*)(ws);
    float*          fnorm = (float*)(ws + 4096);
    float*          wsTop = (float*)(ws + 104448);
    unsigned short* Eb    = (unsigned short*)(ws + 2512896);
    unsigned short* Cb    = (unsigned short*)(ws + 28203008);

    conv_norm_kernel<<<NROW / 4, 256, 0, stream>>>(embeds, Eb, fnorm);
    conv_norm_kernel<<<Pp / 4,   256, 0, stream>>>(centroids, Cb, cnorm);
    mfma_topk_kernel<<<NMB_PAD * 4, 512, 0, stream>>>(Eb, Cb, cnorm, wsTop);
    merge_kernel<<<NROW / 256, 256, 0, stream>>>(wsTop, fnorm, out);
}

// Round 6
// 70.035 us; speedup vs baseline: 1.3390x; 1.3390x over previous
//
#include <hip/hip_runtime.h>
#include <math.h>

#define Cc 512
#define Pp 1024
#define NROW 25088      // B*N = 8*3136
#define BM 128          // rows per block
#define BNP 128         // centroid cols per block (8 pblocks)
#define BK 64           // K tile (8 K-steps)
#define NMB 196         // real mblocks = 25088/128
#define NMB_PAD 200     // padded so mblocks group 8-per-XCD
#define BIAS 4096.f     // makes v = cn+BIAS-2dot strictly positive for packing

typedef short  bf16x8 __attribute__((ext_vector_type(8)));   // 8 bf16 = 4 VGPR
typedef float  f32x4  __attribute__((ext_vector_type(4)));
typedef unsigned short u16x8 __attribute__((ext_vector_type(8)));

__device__ __forceinline__ unsigned short bf16_rne(float f) {
    unsigned int u = __float_as_uint(f);
    return (unsigned short)((u + 0x7fffu + ((u >> 16) & 1u)) >> 16);
}

// ---------------------------------------------------------------------------
// Fused fp32 -> bf16 (RNE) conversion + row squared-norm. One wave per row.
// ---------------------------------------------------------------------------
__global__ __launch_bounds__(256) void conv_norm_kernel(
        const float* __restrict__ src, unsigned short* __restrict__ dst,
        float* __restrict__ nrm) {
    int wid  = blockIdx.x * 4 + (threadIdx.x >> 6);
    int lane = threadIdx.x & 63;
    const float4* r = (const float4*)(src + (size_t)wid * Cc);
    float4 a = r[lane * 2];
    float4 b = r[lane * 2 + 1];
    u16x8 o;
    o[0] = bf16_rne(a.x); o[1] = bf16_rne(a.y); o[2] = bf16_rne(a.z); o[3] = bf16_rne(a.w);
    o[4] = bf16_rne(b.x); o[5] = bf16_rne(b.y); o[6] = bf16_rne(b.z); o[7] = bf16_rne(b.w);
    *(u16x8*)(dst + (size_t)wid * Cc + lane * 8) = o;
    float s = a.x*a.x + a.y*a.y + a.z*a.z + a.w*a.w
            + b.x*b.x + b.y*b.y + b.z*b.z + b.w*b.w;
    #pragma unroll
    for (int m = 1; m < 64; m <<= 1) s += __shfl_xor(s, m);
    if (lane == 0) nrm[wid] = s;
}

// branch-free sorted insert (float), for cross-pblock merges
#define TOP3_INSERT(t0, t1, t2, v)                                  \
    do {                                                            \
        float _n0 = fminf((t0), (v));                               \
        float _h0 = fmaxf((t0), (v));                               \
        float _n1 = fminf((t1), _h0);                               \
        float _h1 = fmaxf((t1), _h0);                               \
        float _n2 = fminf((t2), _h1);                               \
        (t0) = _n0; (t1) = _n1; (t2) = _n2;                         \
    } while (0)

// branch-free sorted insert (packed u32: high-24 float bits | 8-bit col id)
#define TOP3_INS_U32(t0, t1, t2, v)                                 \
    do {                                                            \
        unsigned int _n0 = min((t0), (v));                          \
        unsigned int _h0 = max((t0), (v));                          \
        unsigned int _n1 = min((t1), _h0);                          \
        unsigned int _h1 = max((t1), _h0);                          \
        unsigned int _n2 = min((t2), _h1);                          \
        (t0) = _n0; (t1) = _n1; (t2) = _n2;                         \
    } while (0)

#define GLOAD_LDS16(gp, lp)                                             \
    __builtin_amdgcn_global_load_lds(                                   \
        (const __attribute__((address_space(1))) void*)(const void*)(gp),\
        (__attribute__((address_space(3))) void*)(void*)(lp), 16, 0, 0)

// ---------------------------------------------------------------------------
// Main: 128x128 bf16 MFMA tile, BK=64, double-buffered single-barrier
// pipeline (T3-minimum: STAGE(next) -> compute(cur) -> vmcnt(0)+barrier),
// XOR-swizzled LDS (both-sides), XCD-grouped P-split, swapped-operand MFMA
// so centroids are lane-local in the C fragment (cheap top-3, T12-style).
// Grid: 1600 blocks (200 padded mblocks x 8 pblocks), 256 thr = 4 waves 2x2.
// acc[mc][nr]: cent = p0 + wn*64 + mc*16 + g*4 + reg ; row = row0 + wm*64 + nr*16 + q
// ---------------------------------------------------------------------------
__global__ __launch_bounds__(256) void mfma_topk_kernel(
        const unsigned short* __restrict__ Eb, const unsigned short* __restrict__ Cb,
        const float* __restrict__ cnorm, float* __restrict__ wsTop) {
    // XCD-grouped decode: all 8 pblocks of an mblock land on one XCD
    const int xcd = blockIdx.x & 7;
    const int t8  = blockIdx.x >> 3;          // 0..199
    const int mblock = ((t8 >> 3) << 3) | xcd;
    const int pblock = t8 & 7;
    if (mblock >= NMB) return;                // uniform early-exit (before barriers)

    __shared__ unsigned short lds[2][(BM + BNP) * BK];   // 2 x 32 KB

    const int tid  = threadIdx.x;
    const int lane = tid & 63;
    const int w    = tid >> 6;
    const int wm   = w >> 1;       // 0..1 row half
    const int wn   = w & 1;        // 0..1 cent half
    const int g    = lane >> 4;    // 0..3
    const int q    = lane & 15;    // 0..15
    const int qa   = q & 7;
    const int row0 = mblock * BM;
    const int p0   = pblock * BNP;

    f32x4 acc[4][4];               // [mc][nr]
    #pragma unroll
    for (int mc = 0; mc < 4; ++mc)
        #pragma unroll
        for (int nr = 0; nr < 4; ++nr) acc[mc][nr] = (f32x4){0.f, 0.f, 0.f, 0.f};

    // stage one K-tile into buffer `buf`: A rows then B rows, 8 gload_lds.
    // Source pre-swizzled (slot ^= row&7); LDS dest linear; reader same XOR.
    auto STAGE = [&](int buf, int kk) {
        unsigned short* As = lds[buf];
        unsigned short* Bs = lds[buf] + BM * BK;
        #pragma unroll
        for (int it = 0; it < 4; ++it) {
            int c = tid + it * 256;
            int row = c >> 3;
            int sg  = (c & 7) ^ (row & 7);
            GLOAD_LDS16(Eb + (size_t)(row0 + row) * Cc + kk + sg * 8,
                        (char*)As + c * 16);
        }
        #pragma unroll
        for (int it = 0; it < 4; ++it) {
            int c = tid + it * 256;
            int row = c >> 3;
            int sg  = (c & 7) ^ (row & 7);
            GLOAD_LDS16(Cb + (size_t)(p0 + row) * Cc + kk + sg * 8,
                        (char*)Bs + c * 16);
        }
    };

    // prologue: fill buffer 0
    STAGE(0, 0);
    asm volatile("s_waitcnt vmcnt(0)" ::: "memory");
    __builtin_amdgcn_s_barrier();

    // pipelined K loop: one barrier + one vmcnt drain per step; loads for
    // step t+1 are in flight across the whole compute phase of step t.
    for (int t = 0; t < 8; ++t) {
        const int cur = t & 1;
        if (t < 7) STAGE(cur ^ 1, (t + 1) * BK);

        const unsigned short* As = lds[cur];
        const unsigned short* Bs = lds[cur] + BM * BK;
        #pragma unroll
        for (int ks = 0; ks < 2; ++ks) {
            const int slot = ((ks << 2) | g) ^ qa;   // swizzled 16B slot
            bf16x8 bc[4], ar[4];
            #pragma unroll
            for (int mc = 0; mc < 4; ++mc)
                bc[mc] = *(const bf16x8*)((const char*)Bs +
                        (wn * 64 + mc * 16 + q) * 128 + slot * 16);
            #pragma unroll
            for (int nr = 0; nr < 4; ++nr)
                ar[nr] = *(const bf16x8*)((const char*)As +
                        (wm * 64 + nr * 16 + q) * 128 + slot * 16);
            #pragma unroll
            for (int mc = 0; mc < 4; ++mc)
                #pragma unroll
                for (int nr = 0; nr < 4; ++nr)
                    acc[mc][nr] = __builtin_amdgcn_mfma_f32_16x16x32_bf16(
                        bc[mc], ar[nr], acc[mc][nr], 0, 0, 0);
        }
        asm volatile("s_waitcnt vmcnt(0)" ::: "memory");  // my stage loads landed
        __builtin_amdgcn_s_barrier();                     // all waves: done+landed
    }

    // ---- epilogue: cents lane-local; top-3 per row over 64 cents/wave ----
    float cnb[4][4];
    #pragma unroll
    for (int mc = 0; mc < 4; ++mc)
        #pragma unroll
        for (int reg = 0; reg < 4; ++reg)
            cnb[mc][reg] = cnorm[p0 + wn * 64 + mc * 16 + g * 4 + reg] + BIAS;

    float* tops = (float*)lds;     // alias: [2][BM][3] floats (3 KB), safe now

    #pragma unroll
    for (int nr = 0; nr < 4; ++nr) {
        unsigned int u0 = 0xFFFFFFFFu, u1 = 0xFFFFFFFFu, u2 = 0xFFFFFFFFu;
        #pragma unroll
        for (int mc = 0; mc < 4; ++mc)
            #pragma unroll
            for (int reg = 0; reg < 4; ++reg) {
                float v = fmaf(-2.f, acc[mc][nr][reg], cnb[mc][reg]);  // > 0
                unsigned int cl = (unsigned int)(wn * 64 + mc * 16 + g * 4 + reg);
                unsigned int u = (__float_as_uint(v) & 0xFFFFFF00u) | cl;
                TOP3_INS_U32(u0, u1, u2, u);
            }
        // merge across the 4 g-groups (same row q, disjoint cents)
        #pragma unroll
        for (int mask = 16; mask <= 32; mask <<= 1) {
            unsigned int o0 = (unsigned int)__shfl_xor((int)u0, mask);
            unsigned int o1 = (unsigned int)__shfl_xor((int)u1, mask);
            unsigned int o2 = (unsigned int)__shfl_xor((int)u2, mask);
            TOP3_INS_U32(u0, u1, u2, o0);
            TOP3_INS_U32(u0, u1, u2, o1);
            TOP3_INS_U32(u0, u1, u2, o2);
        }
        if (g == 0) {
            int rl = wm * 64 + nr * 16 + q;
            float* d = tops + ((size_t)wn * BM + rl) * 3;
            d[0] = __uint_as_float(u0 & 0xFFFFFF00u) - BIAS;
            d[1] = __uint_as_float(u1 & 0xFFFFFF00u) - BIAS;
            d[2] = __uint_as_float(u2 & 0xFFFFFF00u) - BIAS;
        }
    }
    __syncthreads();

    if (tid < BM) {
        const float* p = tops + (size_t)tid * 3;
        float a0 = p[0], a1 = p[1], a2 = p[2];
        const float* p1 = tops + ((size_t)BM + tid) * 3;
        TOP3_INSERT(a0, a1, a2, p1[0]);
        TOP3_INSERT(a0, a1, a2, p1[1]);
        TOP3_INSERT(a0, a1, a2, p1[2]);
        float* dst = wsTop + (size_t)(row0 + tid) * 24 + pblock * 3;
        dst[0] = a0; dst[1] = a1; dst[2] = a2;
    }
}

// ---------------------------------------------------------------------------
// Final merge: fold 8 pblocks' top3, add row norm, sqrt + softmin, store.
// ---------------------------------------------------------------------------
__global__ __launch_bounds__(256) void merge_kernel(
        const float* __restrict__ wsTop, const float* __restrict__ fnorm,
        float* __restrict__ out) {
    int r = blockIdx.x * 256 + threadIdx.x;      // 25088 = 98*256 exact
    const float* p = wsTop + (size_t)r * 24;
    float t0 = p[0], t1 = p[1], t2 = p[2];
    #pragma unroll
    for (int pb = 1; pb < 8; ++pb) {
        TOP3_INSERT(t0, t1, t2, p[pb * 3 + 0]);
        TOP3_INSERT(t0, t1, t2, p[pb * 3 + 1]);
        TOP3_INSERT(t0, t1, t2, p[pb * 3 + 2]);
    }
    float fn = fnorm[r];
    float d0 = sqrtf(fmaxf(fn + t0, 0.f));
    float d1 = sqrtf(fmaxf(fn + t1, 0.f));
    float d2 = sqrtf(fmaxf(fn + t2, 0.f));
    float w0 = 1.f / (1.f + __expf(d0 - d1) + __expf(d0 - d2));
    out[r] = w0 * d0;
}

extern "C" void kernel_launch(void* const* d_in, const int* in_sizes, int n_in,
                              void* d_out, int out_size, void* d_ws, size_t ws_size,
                              hipStream_t stream) {
    (void)in_sizes; (void)n_in; (void)out_size; (void)ws_size;
    const float* embeds    = (const float*)d_in[0];   // [8,3136,512] fp32
    const float* centroids = (const float*)d_in[1];   // [1024,512]  fp32
    float* out = (float*)d_out;

    // ws layout (bytes):
    //   cnorm  @ 0         (4 KB)
    //   fnorm  @ 4096      (100,352 B)
    //   wsTop  @ 104448    (25088*8*3*4 = 2,408,448 B)  [row][pblock][3]
    //   Eb     @ 2512896   (25,690,112 B bf16)
    //   Cb     @ 28203008  (1,048,576 B bf16)           total ~27.9 MB
    char* ws = (char*)d_ws;
    float*          cnorm = (float*)(ws);
    float*          fnorm = (float*)(ws + 4096);
    float*          wsTop = (float*)(ws + 104448);
    unsigned short* Eb    = (unsigned short*)(ws + 2512896);
    unsigned short* Cb    = (unsigned short*)(ws + 28203008);

    conv_norm_kernel<<<NROW / 4, 256, 0, stream>>>(embeds, Eb, fnorm);
    conv_norm_kernel<<<Pp / 4,   256, 0, stream>>>(centroids, Cb, cnorm);
    mfma_topk_kernel<<<NMB_PAD * 8, 256, 0, stream>>>(Eb, Cb, cnorm, wsTop);
    merge_kernel<<<NROW / 256, 256, 0, stream>>>(wsTop, fnorm, out);
}